// Round 6
// baseline (581.657 us; speedup 1.0000x reference)
//
#include <hip/hip_runtime.h>

#define N_NODES 100000
#define N_EDGES 6400000
#define IN_DIM 10
#define HIDDEN 16

#define BKT_SHIFT 8
#define BKT_NODES 256                       // nodes per bucket
#define NBKT 391                            // ceil(100000/256)
#define RBIN 38                             // LDS slots per (block,bucket) in pass 1
#define EPB 10240                           // edges per pass-1 block
#define NB1 ((N_EDGES + EPB - 1) / EPB)     // 625 blocks
#define CAPB 18432                          // region slots per bucket (mean 16368, +16 sd)
#define SPLIT 4                             // sub-blocks per bucket in pass 2
#define CHUNK ((CAPB + SPLIT - 1) / SPLIT)  // 4608 records max per sub-block
#define RPT (CHUNK / 512)                   // 9 records max per thread
#define PROW 11                             // 10 feats + count
#define XELEMS (N_NODES * IN_DIM)
#define XE_PER_BLK ((XELEMS + NB1 - 1) / NB1)  // 1600

__device__ __forceinline__ float bf_lo(unsigned u) { return __uint_as_float(u << 16); }
__device__ __forceinline__ float bf_hi(unsigned u) { return __uint_as_float(u & 0xffff0000u); }

// ---------------- Pass 1: xpack prologue + bin edges by dst bucket ----------------
// xpack: x (fp32, 40B rows) -> xp (bf16, 32B-stride rows) so pass-2 gathers touch
// 0.5 cache lines/record instead of 1.5. Independent of binning; runs pre-barrier.
__global__ __launch_bounds__(512) void bin_edges_xpack(const int* __restrict__ src,
                                                       const int* __restrict__ dst,
                                                       const float* __restrict__ x,
                                                       int* __restrict__ gcur,
                                                       unsigned* __restrict__ region,
                                                       unsigned short* __restrict__ xp) {
    __shared__ int lcur[NBKT];
    __shared__ unsigned lbin[NBKT * RBIN];   // 59.4 KB
    for (int b = threadIdx.x; b < NBKT; b += 512) lcur[b] = 0;

    // ---- xpack slice (round-half-up bf16) ----
    int xbase = blockIdx.x * XE_PER_BLK;
    int xend = min(xbase + XE_PER_BLK, XELEMS);
    for (int e = xbase + (int)threadIdx.x; e < xend; e += 512) {
        int row = e / 10;
        int k = e - row * 10;
        unsigned bits = __float_as_uint(x[e]);
        xp[(size_t)row * 16 + k] = (unsigned short)((bits + 0x8000u) >> 16);
    }
    __syncthreads();

    // ---- binning ----
    int base = blockIdx.x * EPB;
    int end = min(base + EPB, N_EDGES);
    for (int i = base + (int)threadIdx.x; i < end; i += 512) {
        int s = src[i], d = dst[i];
        if ((unsigned)s >= N_NODES || (unsigned)d >= N_NODES) continue;
        unsigned pack = (unsigned)s | ((unsigned)(d & (BKT_NODES - 1)) << 17);
        int b = d >> BKT_SHIFT;
        int pos = atomicAdd(&lcur[b], 1);            // LDS int atomic
        if (pos < RBIN) {
            lbin[b * RBIN + pos] = pack;
        } else {
            int g = atomicAdd(&gcur[b], 1);          // rare overflow
            if (g < CAPB) region[(size_t)b * CAPB + g] = pack;
        }
    }
    __syncthreads();

    // drain: one device atomic per nonempty bin, contiguous run write
    for (int b = threadIdx.x; b < NBKT; b += 512) {
        int f = min(lcur[b], RBIN);
        if (f > 0) {
            int g = atomicAdd(&gcur[b], f);
            unsigned* dp = region + (size_t)b * CAPB;
#pragma unroll 4
            for (int j = 0; j < f; ++j) {
                int gg = g + j;
                if (gg < CAPB) dp[gg] = lbin[b * RBIN + j];
            }
        }
    }
}

// ---------------- Pass 2 (fused): counting-sort + register accumulation + epilogue ----
// grid (NBKT, SPLIT). Last sub-block to finish a bucket (device-scope done-counter)
// combines partials and writes the final output -> no third kernel.
__global__ __launch_bounds__(512) void sort_partial_combine(const unsigned short* __restrict__ xp,
                                                            const float* __restrict__ x,
                                                            const int* __restrict__ gcur,
                                                            const unsigned* __restrict__ region,
                                                            float* __restrict__ partial,
                                                            int* __restrict__ done,
                                                            const float* __restrict__ W_l,
                                                            const float* __restrict__ b_l,
                                                            const float* __restrict__ W_r,
                                                            float* __restrict__ out) {
    __shared__ unsigned sorted[CHUNK];       // 18.4 KB
    __shared__ int offs[BKT_NODES + 1];
    __shared__ int cursor[BKT_NODES];
    __shared__ int hist[BKT_NODES];
    __shared__ float sWl[IN_DIM * HIDDEN], sWr[IN_DIM * HIDDEN], sb[HIDDEN];
    __shared__ int s_prev;

    int t = threadIdx.x;
    if (t < BKT_NODES) hist[t] = 0;
    if (t < IN_DIM * HIDDEN) { sWl[t] = W_l[t]; sWr[t] = W_r[t]; }
    if (t < HIDDEN) sb[t] = b_l[t];
    __syncthreads();

    int b = blockIdx.x;
    int sp = blockIdx.y;
    int n = min(gcur[b], CAPB);
    int chunk = (n + SPLIT - 1) / SPLIT;
    int start = sp * chunk;
    int end = min(start + chunk, n);
    const unsigned* reg = region + (size_t)b * CAPB;

    // Phase 1: read records once into registers + histogram local dst
    unsigned rcache[RPT];
    int nr = 0;
    for (int i = start + t; i < end; i += 512) {
        unsigned e = reg[i];                          // coalesced
        rcache[nr++] = e;
        atomicAdd(&hist[(e >> 17) & (BKT_NODES - 1)], 1);
    }
    __syncthreads();

    // Phase 2: exclusive prefix sum of 256 counters on wave 0
    if (t < 64) {
        int base4 = t * 4;
        int h0 = hist[base4], h1 = hist[base4 + 1], h2 = hist[base4 + 2], h3 = hist[base4 + 3];
        int sum4 = h0 + h1 + h2 + h3;
        int run = sum4;
#pragma unroll
        for (int o = 1; o < 64; o <<= 1) {
            int v = __shfl_up(run, o, 64);
            if (t >= o) run += v;
        }
        int excl = run - sum4;
        offs[base4] = excl;
        offs[base4 + 1] = excl + h0;
        offs[base4 + 2] = excl + h0 + h1;
        offs[base4 + 3] = excl + h0 + h1 + h2;
        cursor[base4] = excl;
        cursor[base4 + 1] = excl + h0;
        cursor[base4 + 2] = excl + h0 + h1;
        cursor[base4 + 3] = excl + h0 + h1 + h2;
        if (t == 63) offs[BKT_NODES] = excl + sum4;
    }
    __syncthreads();

    // Phase 3: scatter src ids into per-node segments (from register cache)
    for (int j = 0; j < nr; ++j) {
        unsigned e = rcache[j];
        int local = (e >> 17) & (BKT_NODES - 1);
        int pos = atomicAdd(&cursor[local], 1);
        sorted[pos] = e & 0x1FFFF;
    }
    __syncthreads();

    // Phase 4: thread pair (2l, 2l+1) accumulates node l's segment; bf16 gather (32B rows)
    int local = t >> 1;
    int half = t & 1;
    int s0 = offs[local];
    int s1 = offs[local + 1];
    float acc[IN_DIM];
#pragma unroll
    for (int k = 0; k < IN_DIM; ++k) acc[k] = 0.0f;
    float cnt = 0.0f;
    for (int i = s0 + half; i < s1; i += 2) {
        int s = sorted[i];
        const unsigned* px = (const unsigned*)(xp + (size_t)s * 16);
        uint4 p = *((const uint4*)px);               // bf16 k=0..7, one line
        unsigned q = px[4];                          // bf16 k=8,9
        acc[0] += bf_lo(p.x); acc[1] += bf_hi(p.x);
        acc[2] += bf_lo(p.y); acc[3] += bf_hi(p.y);
        acc[4] += bf_lo(p.z); acc[5] += bf_hi(p.z);
        acc[6] += bf_lo(p.w); acc[7] += bf_hi(p.w);
        acc[8] += bf_lo(q);   acc[9] += bf_hi(q);
        cnt += 1.0f;
    }
#pragma unroll
    for (int k = 0; k < IN_DIM; ++k) acc[k] += __shfl_xor(acc[k], 1, 64);
    cnt += __shfl_xor(cnt, 1, 64);

    // Phase 5: feat-major partial write
    if (half == 0) {
        float* dp = partial + (((size_t)b * SPLIT + sp) * PROW) * BKT_NODES;
#pragma unroll
        for (int k = 0; k < IN_DIM; ++k) dp[(size_t)k * BKT_NODES + local] = acc[k];
        dp[(size_t)10 * BKT_NODES + local] = cnt;
    }

    // Phase 6: device-scope release; last sub-block of the bucket runs the epilogue
    __threadfence();                 // release: partial writes visible device-wide
    __syncthreads();
    if (t == 0) s_prev = atomicAdd(&done[b], 1);
    __syncthreads();
    if (s_prev == SPLIT - 1) {
        __threadfence();             // acquire: see other sub-blocks' partials
        if (t < BKT_NODES) {
            int node = b * BKT_NODES + t;
            if (node < N_NODES) {
                float s[PROW];
#pragma unroll
                for (int k = 0; k < PROW; ++k) s[k] = 0.0f;
#pragma unroll
                for (int sp2 = 0; sp2 < SPLIT; ++sp2) {
                    const float* pp = partial + (((size_t)b * SPLIT + sp2) * PROW) * BKT_NODES + t;
#pragma unroll
                    for (int k = 0; k < PROW; ++k) s[k] += pp[(size_t)k * BKT_NODES];
                }
                float inv = 1.0f / fmaxf(s[10], 1.0f);
                const float* xr = x + (size_t)node * IN_DIM;   // exact fp32 root term
                float o[HIDDEN];
#pragma unroll
                for (int h = 0; h < HIDDEN; ++h) o[h] = sb[h];
#pragma unroll
                for (int k = 0; k < IN_DIM; ++k) {
                    float m = s[k] * inv;
                    float xk = xr[k];
#pragma unroll
                    for (int h = 0; h < HIDDEN; ++h)
                        o[h] += m * sWl[k * HIDDEN + h] + xk * sWr[k * HIDDEN + h];
                }
                float4* op = (float4*)(out + (size_t)node * HIDDEN);
                op[0] = make_float4(o[0], o[1], o[2], o[3]);
                op[1] = make_float4(o[4], o[5], o[6], o[7]);
                op[2] = make_float4(o[8], o[9], o[10], o[11]);
                op[3] = make_float4(o[12], o[13], o[14], o[15]);
            }
        }
    }
}

// ---------------- fallback (round-1 style, correct, slow) for tiny ws ----------------
__global__ void sage_scatter_fb(const float* __restrict__ x, const int* __restrict__ src,
                                const int* __restrict__ dst, float* __restrict__ summed,
                                float* __restrict__ counts) {
    int e = blockIdx.x * blockDim.x + threadIdx.x;
    if (e >= N_EDGES) return;
    int s = src[e], d = dst[e];
    if ((unsigned)s >= N_NODES || (unsigned)d >= N_NODES) return;
    const float* xs = x + (size_t)s * IN_DIM;
    float* sm = summed + (size_t)d * IN_DIM;
#pragma unroll
    for (int k = 0; k < IN_DIM; ++k) atomicAdd(&sm[k], xs[k]);
    atomicAdd(&counts[d], 1.0f);
}

__global__ void sage_out_fb(const float* __restrict__ x, const float* __restrict__ summed,
                            const float* __restrict__ counts, const float* __restrict__ W_l,
                            const float* __restrict__ b_l, const float* __restrict__ W_r,
                            float* __restrict__ out) {
    __shared__ float sWl[IN_DIM * HIDDEN], sWr[IN_DIM * HIDDEN], sb[HIDDEN];
    int t = threadIdx.x;
    if (t < IN_DIM * HIDDEN) { sWl[t] = W_l[t]; sWr[t] = W_r[t]; }
    if (t < HIDDEN) sb[t] = b_l[t];
    __syncthreads();
    int tid = blockIdx.x * blockDim.x + t;
    if (tid >= N_NODES * HIDDEN) return;
    int node = tid >> 4, h = tid & (HIDDEN - 1);
    float inv = 1.0f / fmaxf(counts[node], 1.0f);
    const float* sm = summed + (size_t)node * IN_DIM;
    const float* xr = x + (size_t)node * IN_DIM;
    float acc = sb[h];
#pragma unroll
    for (int k = 0; k < IN_DIM; ++k)
        acc += sm[k] * inv * sWl[k * HIDDEN + h] + xr[k] * sWr[k * HIDDEN + h];
    out[tid] = acc;
}

extern "C" void kernel_launch(void* const* d_in, const int* in_sizes, int n_in,
                              void* d_out, int out_size, void* d_ws, size_t ws_size,
                              hipStream_t stream) {
    const float* x   = (const float*)d_in[0];
    const int*   ei  = (const int*)d_in[1];   // [2, E] flat: first E = src, next E = dst
    const float* W_l = (const float*)d_in[2];
    const float* b_l = (const float*)d_in[3];
    const float* W_r = (const float*)d_in[4];
    float* out = (float*)d_out;
    const int* src = ei;
    const int* dst = ei + N_EDGES;

    const size_t region_off  = 4096;                                        // gcur @0, done @2048
    const size_t region_sz   = (size_t)NBKT * CAPB * 4;                     // 28.83 MB
    const size_t partial_off = region_off + region_sz;
    const size_t partial_sz  = (size_t)NBKT * SPLIT * PROW * BKT_NODES * 4; // 17.62 MB
    const size_t xp_off      = partial_off + partial_sz;                    // 32B-aligned
    const size_t xp_sz       = (size_t)N_NODES * 16 * 2;                    // 3.2 MB
    const size_t need = xp_off + xp_sz;                                     // ~49.7 MB

    if (ws_size >= need) {
        int* gcur = (int*)d_ws;
        int* done = (int*)((char*)d_ws + 2048);
        unsigned* region = (unsigned*)((char*)d_ws + region_off);
        float* partial = (float*)((char*)d_ws + partial_off);
        unsigned short* xp = (unsigned short*)((char*)d_ws + xp_off);

        // gcur + done cursors must be zero every call (ws re-poisoned to 0xAA)
        hipMemsetAsync(d_ws, 0, 4096, stream);

        bin_edges_xpack<<<NB1, 512, 0, stream>>>(src, dst, x, gcur, region, xp);
        dim3 g2(NBKT, SPLIT);
        sort_partial_combine<<<g2, 512, 0, stream>>>(xp, x, gcur, region, partial, done,
                                                     W_l, b_l, W_r, out);
    } else {
        float* summed = (float*)d_ws;
        float* counts = summed + (size_t)N_NODES * IN_DIM;
        hipMemsetAsync(d_ws, 0, (size_t)(N_NODES * IN_DIM + N_NODES) * sizeof(float), stream);
        int threads = 256;
        int eblocks = (N_EDGES + threads - 1) / threads;
        sage_scatter_fb<<<eblocks, threads, 0, stream>>>(x, src, dst, summed, counts);
        int oblocks = (N_NODES * HIDDEN + threads - 1) / threads;
        sage_out_fb<<<oblocks, threads, 0, stream>>>(x, summed, counts, W_l, b_l, W_r, out);
    }
}

// Round 7
// 216.629 us; speedup vs baseline: 2.6850x; 2.6850x over previous
//
#include <hip/hip_runtime.h>

#define N_NODES 100000
#define N_EDGES 6400000
#define IN_DIM 10
#define HIDDEN 16

#define BKT_SHIFT 8
#define BKT_NODES 256                       // nodes per bucket
#define NBKT 391                            // ceil(100000/256)
#define RBIN 38                             // LDS slots per (block,bucket) in pass 1
#define EPB 10240                           // edges per pass-1 block
#define NB1 ((N_EDGES + EPB - 1) / EPB)     // 625 blocks
#define CAPB 18432                          // region slots per bucket (mean 16368, +16 sd)
#define SPLIT 4                             // sub-blocks per bucket in pass 2
#define CHUNK ((CAPB + SPLIT - 1) / SPLIT)  // 4608 records max per sub-block
#define PROW 11                             // 10 feats + count
#define XELEMS (N_NODES * IN_DIM)
#define XE_PER_BLK ((XELEMS + NB1 - 1) / NB1)  // 1600

__device__ __forceinline__ float bf_lo(unsigned u) { return __uint_as_float(u << 16); }
__device__ __forceinline__ float bf_hi(unsigned u) { return __uint_as_float(u & 0xffff0000u); }

// ---------------- Pass 1: xpack prologue + bin edges by dst bucket ----------------
// xpack: x (fp32, 40B rows) -> xp (bf16, 32B-stride rows): pass-2 gathers touch
// exactly 1 cache line / record (20B used) instead of 1.5 lines (40B).
__global__ __launch_bounds__(512) void bin_edges_xpack(const int* __restrict__ src,
                                                       const int* __restrict__ dst,
                                                       const float* __restrict__ x,
                                                       int* __restrict__ gcur,
                                                       unsigned* __restrict__ region,
                                                       unsigned short* __restrict__ xp) {
    __shared__ int lcur[NBKT];
    __shared__ unsigned lbin[NBKT * RBIN];   // 59.4 KB
    for (int b = threadIdx.x; b < NBKT; b += 512) lcur[b] = 0;

    // ---- xpack slice (round-half-up bf16) ----
    int xbase = blockIdx.x * XE_PER_BLK;
    int xend = min(xbase + XE_PER_BLK, XELEMS);
    for (int e = xbase + (int)threadIdx.x; e < xend; e += 512) {
        int row = e / 10;
        int k = e - row * 10;
        unsigned bits = __float_as_uint(x[e]);
        xp[(size_t)row * 16 + k] = (unsigned short)((bits + 0x8000u) >> 16);
    }
    __syncthreads();

    // ---- binning: 1 LDS atomic + 1 LDS store per edge ----
    int base = blockIdx.x * EPB;
    int end = min(base + EPB, N_EDGES);
    for (int i = base + (int)threadIdx.x; i < end; i += 512) {
        int s = src[i], d = dst[i];
        if ((unsigned)s >= N_NODES || (unsigned)d >= N_NODES) continue;
        unsigned pack = (unsigned)s | ((unsigned)(d & (BKT_NODES - 1)) << 17);
        int b = d >> BKT_SHIFT;
        int pos = atomicAdd(&lcur[b], 1);            // LDS int atomic
        if (pos < RBIN) {
            lbin[b * RBIN + pos] = pack;
        } else {
            int g = atomicAdd(&gcur[b], 1);          // rare overflow
            if (g < CAPB) region[(size_t)b * CAPB + g] = pack;
        }
    }
    __syncthreads();

    // drain: one device atomic per nonempty bin, contiguous run write
    for (int b = threadIdx.x; b < NBKT; b += 512) {
        int f = min(lcur[b], RBIN);
        if (f > 0) {
            int g = atomicAdd(&gcur[b], f);
            unsigned* dp = region + (size_t)b * CAPB;
#pragma unroll 4
            for (int j = 0; j < f; ++j) {
                int gg = g + j;
                if (gg < CAPB) dp[gg] = lbin[b * RBIN + j];
            }
        }
    }
}

// ---------------- Pass 2: counting-sort per sub-block, register accumulation ----------------
// grid (NBKT, SPLIT), 512 threads. No float atomics, no fences, no scratch arrays:
//   hist (1 int LDS atomic/rec) -> wave scan -> scatter (1 atomic + 1 store/rec)
//   -> thread-pair per local node walks its sorted segment; bf16 x-row gather.
__global__ __launch_bounds__(512) void bucket_sort_partial(const unsigned short* __restrict__ xp,
                                                           const int* __restrict__ gcur,
                                                           const unsigned* __restrict__ region,
                                                           float* __restrict__ partial) {
    __shared__ unsigned sorted[CHUNK];       // 18.4 KB
    __shared__ int offs[BKT_NODES + 1];
    __shared__ int cursor[BKT_NODES];
    __shared__ int hist[BKT_NODES];

    int t = threadIdx.x;
    if (t < BKT_NODES) hist[t] = 0;
    __syncthreads();

    int b = blockIdx.x;
    int sp = blockIdx.y;
    int n = min(gcur[b], CAPB);
    int chunk = (n + SPLIT - 1) / SPLIT;
    int start = sp * chunk;
    int end = min(start + chunk, n);
    const unsigned* reg = region + (size_t)b * CAPB;

    // Phase 1: histogram of local dst (coalesced region read)
    for (int i = start + t; i < end; i += 512) {
        int local = (reg[i] >> 17) & (BKT_NODES - 1);
        atomicAdd(&hist[local], 1);
    }
    __syncthreads();

    // Phase 2: exclusive prefix sum of 256 counters on wave 0
    if (t < 64) {
        int base4 = t * 4;
        int h0 = hist[base4], h1 = hist[base4 + 1], h2 = hist[base4 + 2], h3 = hist[base4 + 3];
        int sum4 = h0 + h1 + h2 + h3;
        int run = sum4;
#pragma unroll
        for (int o = 1; o < 64; o <<= 1) {
            int v = __shfl_up(run, o, 64);
            if (t >= o) run += v;
        }
        int excl = run - sum4;
        offs[base4] = excl;
        offs[base4 + 1] = excl + h0;
        offs[base4 + 2] = excl + h0 + h1;
        offs[base4 + 3] = excl + h0 + h1 + h2;
        cursor[base4] = excl;
        cursor[base4 + 1] = excl + h0;
        cursor[base4 + 2] = excl + h0 + h1;
        cursor[base4 + 3] = excl + h0 + h1 + h2;
        if (t == 63) offs[BKT_NODES] = excl + sum4;
    }
    __syncthreads();

    // Phase 3: scatter src ids into per-node segments (re-read region: L2-warm)
    for (int i = start + t; i < end; i += 512) {
        unsigned e = reg[i];
        int local = (e >> 17) & (BKT_NODES - 1);
        int pos = atomicAdd(&cursor[local], 1);
        sorted[pos] = e & 0x1FFFF;
    }
    __syncthreads();

    // Phase 4: thread pair (2l, 2l+1) accumulates node l's segment; bf16 rows, 1 line each
    int local = t >> 1;
    int half = t & 1;
    int s0 = offs[local];
    int s1 = offs[local + 1];
    float acc[IN_DIM];
#pragma unroll
    for (int k = 0; k < IN_DIM; ++k) acc[k] = 0.0f;
    float cnt = 0.0f;
    for (int i = s0 + half; i < s1; i += 2) {
        int s = sorted[i];
        const unsigned* px = (const unsigned*)(xp + (size_t)s * 16);
        uint4 p = *((const uint4*)px);               // bf16 k=0..7
        unsigned q = px[4];                          // bf16 k=8,9
        acc[0] += bf_lo(p.x); acc[1] += bf_hi(p.x);
        acc[2] += bf_lo(p.y); acc[3] += bf_hi(p.y);
        acc[4] += bf_lo(p.z); acc[5] += bf_hi(p.z);
        acc[6] += bf_lo(p.w); acc[7] += bf_hi(p.w);
        acc[8] += bf_lo(q);   acc[9] += bf_hi(q);
        cnt += 1.0f;
    }
#pragma unroll
    for (int k = 0; k < IN_DIM; ++k) acc[k] += __shfl_xor(acc[k], 1, 64);
    cnt += __shfl_xor(cnt, 1, 64);

    // Phase 5: feat-major partial write
    if (half == 0) {
        float* dp = partial + (((size_t)b * SPLIT + sp) * PROW) * BKT_NODES;
#pragma unroll
        for (int k = 0; k < IN_DIM; ++k) dp[(size_t)k * BKT_NODES + local] = acc[k];
        dp[(size_t)10 * BKT_NODES + local] = cnt;
    }
}

// ---------------- Pass 3: combine partials + fused mean/GEMV/bias ----------------
__global__ __launch_bounds__(512) void combine_out(const float* __restrict__ x,
                                                   const float* __restrict__ partial,
                                                   const float* __restrict__ W_l,
                                                   const float* __restrict__ b_l,
                                                   const float* __restrict__ W_r,
                                                   float* __restrict__ out) {
    __shared__ float sWl[IN_DIM * HIDDEN], sWr[IN_DIM * HIDDEN], sb[HIDDEN];
    int t = threadIdx.x;
    if (t < IN_DIM * HIDDEN) { sWl[t] = W_l[t]; sWr[t] = W_r[t]; }
    if (t < HIDDEN) sb[t] = b_l[t];
    __syncthreads();

    int node = blockIdx.x * 512 + t;
    if (node >= N_NODES) return;
    int b = node >> BKT_SHIFT;
    int local = node & (BKT_NODES - 1);

    float s[PROW];
#pragma unroll
    for (int k = 0; k < PROW; ++k) s[k] = 0.0f;
#pragma unroll
    for (int sp = 0; sp < SPLIT; ++sp) {
        const float* pp = partial + (((size_t)b * SPLIT + sp) * PROW) * BKT_NODES + local;
#pragma unroll
        for (int k = 0; k < PROW; ++k) s[k] += pp[(size_t)k * BKT_NODES];  // coalesced
    }

    float inv = 1.0f / fmaxf(s[10], 1.0f);
    const float* xp = x + (size_t)node * IN_DIM;   // exact fp32 root term
    float m[IN_DIM], xr[IN_DIM];
#pragma unroll
    for (int k = 0; k < IN_DIM; ++k) { m[k] = s[k] * inv; xr[k] = xp[k]; }

    float o[HIDDEN];
#pragma unroll
    for (int h = 0; h < HIDDEN; ++h) o[h] = sb[h];
#pragma unroll
    for (int k = 0; k < IN_DIM; ++k) {
#pragma unroll
        for (int h = 0; h < HIDDEN; ++h)
            o[h] += m[k] * sWl[k * HIDDEN + h] + xr[k] * sWr[k * HIDDEN + h];
    }
    float4* op = (float4*)(out + (size_t)node * HIDDEN);
    op[0] = make_float4(o[0], o[1], o[2], o[3]);
    op[1] = make_float4(o[4], o[5], o[6], o[7]);
    op[2] = make_float4(o[8], o[9], o[10], o[11]);
    op[3] = make_float4(o[12], o[13], o[14], o[15]);
}

// ---------------- fallback (round-1 style, correct, slow) for tiny ws ----------------
__global__ void sage_scatter_fb(const float* __restrict__ x, const int* __restrict__ src,
                                const int* __restrict__ dst, float* __restrict__ summed,
                                float* __restrict__ counts) {
    int e = blockIdx.x * blockDim.x + threadIdx.x;
    if (e >= N_EDGES) return;
    int s = src[e], d = dst[e];
    if ((unsigned)s >= N_NODES || (unsigned)d >= N_NODES) return;
    const float* xs = x + (size_t)s * IN_DIM;
    float* sm = summed + (size_t)d * IN_DIM;
#pragma unroll
    for (int k = 0; k < IN_DIM; ++k) atomicAdd(&sm[k], xs[k]);
    atomicAdd(&counts[d], 1.0f);
}

__global__ void sage_out_fb(const float* __restrict__ x, const float* __restrict__ summed,
                            const float* __restrict__ counts, const float* __restrict__ W_l,
                            const float* __restrict__ b_l, const float* __restrict__ W_r,
                            float* __restrict__ out) {
    __shared__ float sWl[IN_DIM * HIDDEN], sWr[IN_DIM * HIDDEN], sb[HIDDEN];
    int t = threadIdx.x;
    if (t < IN_DIM * HIDDEN) { sWl[t] = W_l[t]; sWr[t] = W_r[t]; }
    if (t < HIDDEN) sb[t] = b_l[t];
    __syncthreads();
    int tid = blockIdx.x * blockDim.x + t;
    if (tid >= N_NODES * HIDDEN) return;
    int node = tid >> 4, h = tid & (HIDDEN - 1);
    float inv = 1.0f / fmaxf(counts[node], 1.0f);
    const float* sm = summed + (size_t)node * IN_DIM;
    const float* xr = x + (size_t)node * IN_DIM;
    float acc = sb[h];
#pragma unroll
    for (int k = 0; k < IN_DIM; ++k)
        acc += sm[k] * inv * sWl[k * HIDDEN + h] + xr[k] * sWr[k * HIDDEN + h];
    out[tid] = acc;
}

extern "C" void kernel_launch(void* const* d_in, const int* in_sizes, int n_in,
                              void* d_out, int out_size, void* d_ws, size_t ws_size,
                              hipStream_t stream) {
    const float* x   = (const float*)d_in[0];
    const int*   ei  = (const int*)d_in[1];   // [2, E] flat: first E = src, next E = dst
    const float* W_l = (const float*)d_in[2];
    const float* b_l = (const float*)d_in[3];
    const float* W_r = (const float*)d_in[4];
    float* out = (float*)d_out;
    const int* src = ei;
    const int* dst = ei + N_EDGES;

    const size_t region_off  = 4096;
    const size_t region_sz   = (size_t)NBKT * CAPB * 4;                     // 28.83 MB
    const size_t partial_off = region_off + region_sz;
    const size_t partial_sz  = (size_t)NBKT * SPLIT * PROW * BKT_NODES * 4; // 17.62 MB
    const size_t xp_off      = partial_off + partial_sz;                    // 32B-aligned
    const size_t xp_sz       = (size_t)N_NODES * 16 * 2;                    // 3.2 MB
    const size_t need = xp_off + xp_sz;                                     // ~49.7 MB

    if (ws_size >= need) {
        int* gcur = (int*)d_ws;
        unsigned* region = (unsigned*)((char*)d_ws + region_off);
        float* partial = (float*)((char*)d_ws + partial_off);
        unsigned short* xp = (unsigned short*)((char*)d_ws + xp_off);

        // gcur must be zero every call (ws re-poisoned to 0xAA)
        hipMemsetAsync(gcur, 0, NBKT * sizeof(int), stream);

        bin_edges_xpack<<<NB1, 512, 0, stream>>>(src, dst, x, gcur, region, xp);
        dim3 g2(NBKT, SPLIT);
        bucket_sort_partial<<<g2, 512, 0, stream>>>(xp, gcur, region, partial);
        combine_out<<<(N_NODES + 511) / 512, 512, 0, stream>>>(x, partial, W_l, b_l, W_r, out);
    } else {
        float* summed = (float*)d_ws;
        float* counts = summed + (size_t)N_NODES * IN_DIM;
        hipMemsetAsync(d_ws, 0, (size_t)(N_NODES * IN_DIM + N_NODES) * sizeof(float), stream);
        int threads = 256;
        int eblocks = (N_EDGES + threads - 1) / threads;
        sage_scatter_fb<<<eblocks, threads, 0, stream>>>(x, src, dst, summed, counts);
        int oblocks = (N_NODES * HIDDEN + threads - 1) / threads;
        sage_out_fb<<<oblocks, threads, 0, stream>>>(x, summed, counts, W_l, b_l, W_r, out);
    }
}

// Round 8
// 209.261 us; speedup vs baseline: 2.7796x; 1.0352x over previous
//
#include <hip/hip_runtime.h>

#define N_NODES 100000
#define N_EDGES 6400000
#define IN_DIM 10
#define HIDDEN 16

#define BKT_SHIFT 8
#define BKT_NODES 256                       // nodes per bucket
#define NBKT 391                            // ceil(100000/256)
#define RBIN 24                             // LDS slots per (block,bucket): fill λ=13.1, 3σ=24
#define EPB 5120                            // edges per pass-1 block (halved: 39KB LDS -> 4 blk/CU)
#define NB1 ((N_EDGES + EPB - 1) / EPB)     // 1250 blocks
#define CAPB 18432                          // region slots per bucket (mean 16368, +16 sd)
#define SPLIT 4                             // sub-blocks per bucket in pass 2
#define CHUNK ((CAPB + SPLIT - 1) / SPLIT)  // 4608 records max per sub-block
#define PROW 11                             // 10 feats + count
#define XELEMS (N_NODES * IN_DIM)
#define XE_PER_BLK ((XELEMS + NB1 - 1) / NB1)  // 800

__device__ __forceinline__ float bf_lo(unsigned u) { return __uint_as_float(u << 16); }
__device__ __forceinline__ float bf_hi(unsigned u) { return __uint_as_float(u & 0xffff0000u); }

// ---------------- Pass 1: xpack prologue + bin edges by dst bucket ----------------
// LDS cut to ~39KB (lcur 1.6K + lbin 37.5K) -> 4 blocks/CU (32 waves) to test the
// latency-bound hypothesis for the binning pattern (was 26% occupancy at 60KB).
__global__ __launch_bounds__(512) void bin_edges_xpack(const int* __restrict__ src,
                                                       const int* __restrict__ dst,
                                                       const float* __restrict__ x,
                                                       int* __restrict__ gcur,
                                                       unsigned* __restrict__ region,
                                                       unsigned short* __restrict__ xp) {
    __shared__ int lcur[NBKT];
    __shared__ unsigned lbin[NBKT * RBIN];   // 37.5 KB
    for (int b = threadIdx.x; b < NBKT; b += 512) lcur[b] = 0;

    // ---- xpack slice (round-half-up bf16) ----
    int xbase = blockIdx.x * XE_PER_BLK;
    int xend = min(xbase + XE_PER_BLK, XELEMS);
    for (int e = xbase + (int)threadIdx.x; e < xend; e += 512) {
        int row = e / 10;
        int k = e - row * 10;
        unsigned bits = __float_as_uint(x[e]);
        xp[(size_t)row * 16 + k] = (unsigned short)((bits + 0x8000u) >> 16);
    }
    __syncthreads();

    // ---- binning: 1 LDS atomic + 1 LDS store per edge ----
    int base = blockIdx.x * EPB;
    int end = min(base + EPB, N_EDGES);
    for (int i = base + (int)threadIdx.x; i < end; i += 512) {
        int s = src[i], d = dst[i];
        if ((unsigned)s >= N_NODES || (unsigned)d >= N_NODES) continue;
        unsigned pack = (unsigned)s | ((unsigned)(d & (BKT_NODES - 1)) << 17);
        int b = d >> BKT_SHIFT;
        int pos = atomicAdd(&lcur[b], 1);            // LDS int atomic
        if (pos < RBIN) {
            lbin[b * RBIN + pos] = pack;
        } else {
            int g = atomicAdd(&gcur[b], 1);          // rare overflow (~0.2% of bins)
            if (g < CAPB) region[(size_t)b * CAPB + g] = pack;
        }
    }
    __syncthreads();

    // drain: one device atomic per nonempty bin, contiguous run write
    for (int b = threadIdx.x; b < NBKT; b += 512) {
        int f = min(lcur[b], RBIN);
        if (f > 0) {
            int g = atomicAdd(&gcur[b], f);
            unsigned* dp = region + (size_t)b * CAPB;
#pragma unroll 4
            for (int j = 0; j < f; ++j) {
                int gg = g + j;
                if (gg < CAPB) dp[gg] = lbin[b * RBIN + j];
            }
        }
    }
}

// ---------------- Pass 2: counting-sort per sub-block, register accumulation ----------------
__global__ __launch_bounds__(512) void bucket_sort_partial(const unsigned short* __restrict__ xp,
                                                           const int* __restrict__ gcur,
                                                           const unsigned* __restrict__ region,
                                                           float* __restrict__ partial) {
    __shared__ unsigned sorted[CHUNK];       // 18.4 KB
    __shared__ int offs[BKT_NODES + 1];
    __shared__ int cursor[BKT_NODES];
    __shared__ int hist[BKT_NODES];

    int t = threadIdx.x;
    if (t < BKT_NODES) hist[t] = 0;
    __syncthreads();

    int b = blockIdx.x;
    int sp = blockIdx.y;
    int n = min(gcur[b], CAPB);
    int chunk = (n + SPLIT - 1) / SPLIT;
    int start = sp * chunk;
    int end = min(start + chunk, n);
    const unsigned* reg = region + (size_t)b * CAPB;

    // Phase 1: histogram of local dst (coalesced region read)
    for (int i = start + t; i < end; i += 512) {
        int local = (reg[i] >> 17) & (BKT_NODES - 1);
        atomicAdd(&hist[local], 1);
    }
    __syncthreads();

    // Phase 2: exclusive prefix sum of 256 counters on wave 0
    if (t < 64) {
        int base4 = t * 4;
        int h0 = hist[base4], h1 = hist[base4 + 1], h2 = hist[base4 + 2], h3 = hist[base4 + 3];
        int sum4 = h0 + h1 + h2 + h3;
        int run = sum4;
#pragma unroll
        for (int o = 1; o < 64; o <<= 1) {
            int v = __shfl_up(run, o, 64);
            if (t >= o) run += v;
        }
        int excl = run - sum4;
        offs[base4] = excl;
        offs[base4 + 1] = excl + h0;
        offs[base4 + 2] = excl + h0 + h1;
        offs[base4 + 3] = excl + h0 + h1 + h2;
        cursor[base4] = excl;
        cursor[base4 + 1] = excl + h0;
        cursor[base4 + 2] = excl + h0 + h1;
        cursor[base4 + 3] = excl + h0 + h1 + h2;
        if (t == 63) offs[BKT_NODES] = excl + sum4;
    }
    __syncthreads();

    // Phase 3: scatter src ids into per-node segments (re-read region: L2-warm)
    for (int i = start + t; i < end; i += 512) {
        unsigned e = reg[i];
        int local = (e >> 17) & (BKT_NODES - 1);
        int pos = atomicAdd(&cursor[local], 1);
        sorted[pos] = e & 0x1FFFF;
    }
    __syncthreads();

    // Phase 4: thread pair (2l, 2l+1) accumulates node l's segment; bf16 rows, 1 line each
    int local = t >> 1;
    int half = t & 1;
    int s0 = offs[local];
    int s1 = offs[local + 1];
    float acc[IN_DIM];
#pragma unroll
    for (int k = 0; k < IN_DIM; ++k) acc[k] = 0.0f;
    float cnt = 0.0f;
    for (int i = s0 + half; i < s1; i += 2) {
        int s = sorted[i];
        const unsigned* px = (const unsigned*)(xp + (size_t)s * 16);
        uint4 p = *((const uint4*)px);               // bf16 k=0..7
        unsigned q = px[4];                          // bf16 k=8,9
        acc[0] += bf_lo(p.x); acc[1] += bf_hi(p.x);
        acc[2] += bf_lo(p.y); acc[3] += bf_hi(p.y);
        acc[4] += bf_lo(p.z); acc[5] += bf_hi(p.z);
        acc[6] += bf_lo(p.w); acc[7] += bf_hi(p.w);
        acc[8] += bf_lo(q);   acc[9] += bf_hi(q);
        cnt += 1.0f;
    }
#pragma unroll
    for (int k = 0; k < IN_DIM; ++k) acc[k] += __shfl_xor(acc[k], 1, 64);
    cnt += __shfl_xor(cnt, 1, 64);

    // Phase 5: feat-major partial write
    if (half == 0) {
        float* dp = partial + (((size_t)b * SPLIT + sp) * PROW) * BKT_NODES;
#pragma unroll
        for (int k = 0; k < IN_DIM; ++k) dp[(size_t)k * BKT_NODES + local] = acc[k];
        dp[(size_t)10 * BKT_NODES + local] = cnt;
    }
}

// ---------------- Pass 3: combine partials + fused mean/GEMV/bias ----------------
__global__ __launch_bounds__(512) void combine_out(const float* __restrict__ x,
                                                   const float* __restrict__ partial,
                                                   const float* __restrict__ W_l,
                                                   const float* __restrict__ b_l,
                                                   const float* __restrict__ W_r,
                                                   float* __restrict__ out) {
    __shared__ float sWl[IN_DIM * HIDDEN], sWr[IN_DIM * HIDDEN], sb[HIDDEN];
    int t = threadIdx.x;
    if (t < IN_DIM * HIDDEN) { sWl[t] = W_l[t]; sWr[t] = W_r[t]; }
    if (t < HIDDEN) sb[t] = b_l[t];
    __syncthreads();

    int node = blockIdx.x * 512 + t;
    if (node >= N_NODES) return;
    int b = node >> BKT_SHIFT;
    int local = node & (BKT_NODES - 1);

    float s[PROW];
#pragma unroll
    for (int k = 0; k < PROW; ++k) s[k] = 0.0f;
#pragma unroll
    for (int sp = 0; sp < SPLIT; ++sp) {
        const float* pp = partial + (((size_t)b * SPLIT + sp) * PROW) * BKT_NODES + local;
#pragma unroll
        for (int k = 0; k < PROW; ++k) s[k] += pp[(size_t)k * BKT_NODES];  // coalesced
    }

    float inv = 1.0f / fmaxf(s[10], 1.0f);
    const float* xp = x + (size_t)node * IN_DIM;   // exact fp32 root term
    float m[IN_DIM], xr[IN_DIM];
#pragma unroll
    for (int k = 0; k < IN_DIM; ++k) { m[k] = s[k] * inv; xr[k] = xp[k]; }

    float o[HIDDEN];
#pragma unroll
    for (int h = 0; h < HIDDEN; ++h) o[h] = sb[h];
#pragma unroll
    for (int k = 0; k < IN_DIM; ++k) {
#pragma unroll
        for (int h = 0; h < HIDDEN; ++h)
            o[h] += m[k] * sWl[k * HIDDEN + h] + xr[k] * sWr[k * HIDDEN + h];
    }
    float4* op = (float4*)(out + (size_t)node * HIDDEN);
    op[0] = make_float4(o[0], o[1], o[2], o[3]);
    op[1] = make_float4(o[4], o[5], o[6], o[7]);
    op[2] = make_float4(o[8], o[9], o[10], o[11]);
    op[3] = make_float4(o[12], o[13], o[14], o[15]);
}

// ---------------- fallback (round-1 style, correct, slow) for tiny ws ----------------
__global__ void sage_scatter_fb(const float* __restrict__ x, const int* __restrict__ src,
                                const int* __restrict__ dst, float* __restrict__ summed,
                                float* __restrict__ counts) {
    int e = blockIdx.x * blockDim.x + threadIdx.x;
    if (e >= N_EDGES) return;
    int s = src[e], d = dst[e];
    if ((unsigned)s >= N_NODES || (unsigned)d >= N_NODES) return;
    const float* xs = x + (size_t)s * IN_DIM;
    float* sm = summed + (size_t)d * IN_DIM;
#pragma unroll
    for (int k = 0; k < IN_DIM; ++k) atomicAdd(&sm[k], xs[k]);
    atomicAdd(&counts[d], 1.0f);
}

__global__ void sage_out_fb(const float* __restrict__ x, const float* __restrict__ summed,
                            const float* __restrict__ counts, const float* __restrict__ W_l,
                            const float* __restrict__ b_l, const float* __restrict__ W_r,
                            float* __restrict__ out) {
    __shared__ float sWl[IN_DIM * HIDDEN], sWr[IN_DIM * HIDDEN], sb[HIDDEN];
    int t = threadIdx.x;
    if (t < IN_DIM * HIDDEN) { sWl[t] = W_l[t]; sWr[t] = W_r[t]; }
    if (t < HIDDEN) sb[t] = b_l[t];
    __syncthreads();
    int tid = blockIdx.x * blockDim.x + t;
    if (tid >= N_NODES * HIDDEN) return;
    int node = tid >> 4, h = tid & (HIDDEN - 1);
    float inv = 1.0f / fmaxf(counts[node], 1.0f);
    const float* sm = summed + (size_t)node * IN_DIM;
    const float* xr = x + (size_t)node * IN_DIM;
    float acc = sb[h];
#pragma unroll
    for (int k = 0; k < IN_DIM; ++k)
        acc += sm[k] * inv * sWl[k * HIDDEN + h] + xr[k] * sWr[k * HIDDEN + h];
    out[tid] = acc;
}

extern "C" void kernel_launch(void* const* d_in, const int* in_sizes, int n_in,
                              void* d_out, int out_size, void* d_ws, size_t ws_size,
                              hipStream_t stream) {
    const float* x   = (const float*)d_in[0];
    const int*   ei  = (const int*)d_in[1];   // [2, E] flat: first E = src, next E = dst
    const float* W_l = (const float*)d_in[2];
    const float* b_l = (const float*)d_in[3];
    const float* W_r = (const float*)d_in[4];
    float* out = (float*)d_out;
    const int* src = ei;
    const int* dst = ei + N_EDGES;

    const size_t region_off  = 4096;
    const size_t region_sz   = (size_t)NBKT * CAPB * 4;                     // 28.83 MB
    const size_t partial_off = region_off + region_sz;
    const size_t partial_sz  = (size_t)NBKT * SPLIT * PROW * BKT_NODES * 4; // 17.62 MB
    const size_t xp_off      = partial_off + partial_sz;                    // 32B-aligned
    const size_t xp_sz       = (size_t)N_NODES * 16 * 2;                    // 3.2 MB
    const size_t need = xp_off + xp_sz;                                     // ~49.7 MB

    if (ws_size >= need) {
        int* gcur = (int*)d_ws;
        unsigned* region = (unsigned*)((char*)d_ws + region_off);
        float* partial = (float*)((char*)d_ws + partial_off);
        unsigned short* xp = (unsigned short*)((char*)d_ws + xp_off);

        // gcur must be zero every call (ws re-poisoned to 0xAA)
        hipMemsetAsync(gcur, 0, NBKT * sizeof(int), stream);

        bin_edges_xpack<<<NB1, 512, 0, stream>>>(src, dst, x, gcur, region, xp);
        dim3 g2(NBKT, SPLIT);
        bucket_sort_partial<<<g2, 512, 0, stream>>>(xp, gcur, region, partial);
        combine_out<<<(N_NODES + 511) / 512, 512, 0, stream>>>(x, partial, W_l, b_l, W_r, out);
    } else {
        float* summed = (float*)d_ws;
        float* counts = summed + (size_t)N_NODES * IN_DIM;
        hipMemsetAsync(d_ws, 0, (size_t)(N_NODES * IN_DIM + N_NODES) * sizeof(float), stream);
        int threads = 256;
        int eblocks = (N_EDGES + threads - 1) / threads;
        sage_scatter_fb<<<eblocks, threads, 0, stream>>>(x, src, dst, summed, counts);
        int oblocks = (N_NODES * HIDDEN + threads - 1) / threads;
        sage_out_fb<<<oblocks, threads, 0, stream>>>(x, summed, counts, W_l, b_l, W_r, out);
    }
}